// Round 8
// baseline (289.287 us; speedup 1.0000x reference)
//
#include <hip/hip_runtime.h>
#include <hip/hip_bf16.h>
#include <math.h>

// Problem constants
#define BB 8
#define CC 256
#define TT 8192
#define EPSF 1e-5f

typedef short v8s __attribute__((ext_vector_type(8)));
typedef float v4f __attribute__((ext_vector_type(4)));

#define MFMA(a, b, c) __builtin_amdgcn_mfma_f32_16x16x32_bf16((a), (b), (c), 0, 0, 0)

// MFMA 16x16x32 bf16 fragment conventions (m89/m91 verified):
//   A[m][k]: m = lane&15, k = (lane>>4)*8 + j   (8 contiguous k per lane)
//   B[k][n]: n = lane&15, k = (lane>>4)*8 + j
//   C/D:     col = lane&15, row = (lane>>4)*4 + reg
//
// REGISTER MODEL (r1-r7): 512-thread blocks are pinned at <=128 arch VGPRs;
// demand above that spills ~150MB/pass. v5 (r7) fit at 112 -> clean counters,
// but LDS (146KB) capped residency at 1 block/CU -> latency-bound (all pipes
// <10%). v6 (this round): halve LDS to 65KB -> 2 blocks/CU, 16 waves.

// Workspace layout (float offsets); ~37.6 MB
#define OFF_WKV 0               // Wkv bf16 [h][type][64][256]  -> 131072 ushort
#define OFF_WPJ 65536           // Wproj bf16 [256][256]        -> 65536 ushort
#define OFF_UPART 98304         // fp32 [512 p][4h][64][64]     -> 8388608 floats
#define OFF_ZPART 8486912       // fp32 [512 p][8 w][64]        -> 262144 floats
#define OFF_KV 8749056          // fp32 [b][h][64 d][64 e]      -> 131072 floats
#define OFF_PT 8880128          // Pt bf16 [b][c][256 c2]       -> 524288 ushort
#define OFF_MBF 9142272         // M bf16 [b][o][c]             -> 524288 ushort

__device__ __forceinline__ unsigned short f2bf(float f) {
  __hip_bfloat16 h = __float2bfloat16(f);
  return __builtin_bit_cast(unsigned short, h);
}
__device__ __forceinline__ float bf2f(unsigned short u) {
  return __bfloat162float(__builtin_bit_cast(__hip_bfloat16, u));
}
__device__ __forceinline__ unsigned int pack2(float lo, float hi) {
  return (unsigned int)f2bf(lo) | ((unsigned int)f2bf(hi) << 16);
}
// Swizzled pitch-32 [64 rows][32 cols] ushort tile: 16B chunk index XORed with
// row bits -> ds_read_b128-aligned, banks spread (write ~2-way, read ~2-4-way).
__device__ __forceinline__ int swz_w(int row, int col) {
  return row * 32 + ((((col >> 3) ^ (row & 3) ^ ((row >> 2) & 3)) & 3) << 3) +
         (col & 7);
}
__device__ __forceinline__ int swz_r(int row, int q) {
  return row * 32 + (((q ^ (row & 3) ^ ((row >> 2) & 3)) & 3) << 3);
}

// ---------------------------------------------------------------------------
// k0: pack weights to bf16. rows 0..511: Wkv[h][type][d][c]; rows 512..767: Wproj.
// ---------------------------------------------------------------------------
__global__ void k0_pack(const float* __restrict__ Wpre,
                        const float* __restrict__ Wproj,
                        float* __restrict__ ws) {
  const int r = blockIdx.x;
  const int c = threadIdx.x;
  if (r < 512) {
    const int h = r >> 7, type = (r >> 6) & 1, d = r & 63;
    const int src = h * 192 + 64 + type * 64 + d;
    ((unsigned short*)(ws + OFF_WKV))[r * 256 + c] = f2bf(Wpre[(size_t)src * 256 + c]);
  } else {
    const int rr = r - 512;
    ((unsigned short*)(ws + OFF_WPJ))[rr * 256 + c] = f2bf(Wproj[(size_t)rr * 256 + c]);
  }
}

// ---------------------------------------------------------------------------
// k1 (v6, 2 blocks/CU): grid 512 = 8b x 64 chunks of 128 t; 8 waves; wave =
// (head h = w>>1, t-half = w&1). Per 64-t sub:
//   [A] xs ready -> k-pass (64 MFMA) -> exp -> e to R2; v-pass (64 MFMA)
//   [B] xs reads done -> v to R1 (OVERLAYS xs); issue next-sub x prefetch
//   [C] e+v ready -> U rows [thalf*32..+32) += e @ v^T (16 MFMA, both slices)
//   [D, sub<1] v reads done -> stage prefetched x into R1
// LDS: R1 [0,16896) xs[64][264] / v-overlay [4h][2s][64][32] swizzled;
//      R2 [16896,33280) e [4h][2s][64][32] swizzled. 66560 B -> 2 blocks/CU.
// Peak regs ~119 <= 128 (prefetch issued after v-write, when acc is dead).
// Hazards: e written (A..B), read (C..D') -> next write after A' > D ok.
// v written (B..C), read (C..D); xs staged after D, read after A'.
// ---------------------------------------------------------------------------
__global__ __launch_bounds__(512, 2) void k1_kv(const float* __restrict__ x,
                                                float* __restrict__ ws) {
  __shared__ unsigned short lds[33280];

  const int tid = threadIdx.x;
  const int w = tid >> 6, lane = tid & 63, q = lane >> 4, cl = lane & 15;
  const int h = w >> 1, thalf = w & 1;
  const int tw0 = thalf * 32;
  const int bi = blockIdx.x;  // 0..511
  const int b = bi >> 6, chunk = bi & 63;
  const int t0 = chunk * 128;
  const float* xb = x + (size_t)b * (CC * TT);
  const unsigned short* wk =
      (const unsigned short*)(ws + OFF_WKV) + (size_t)((h * 2 + 0) * 64) * 256;
  const unsigned short* wv =
      (const unsigned short*)(ws + OFF_WKV) + (size_t)((h * 2 + 1) * 64) * 256;
  unsigned short* ekw = &lds[16896 + h * 4096 + thalf * 2048];  // own e buf
  unsigned short* vbw_ = &lds[h * 4096 + thalf * 2048];         // own v buf

  v4f Uacc[2][4];
#pragma unroll
  for (int i = 0; i < 2; ++i)
#pragma unroll
    for (int j = 0; j < 4; ++j) Uacc[i][j] = (v4f){0.f, 0.f, 0.f, 0.f};
  float zacc[4][4];
#pragma unroll
  for (int i = 0; i < 4; ++i)
#pragma unroll
    for (int j = 0; j < 4; ++j) zacc[i][j] = 0.f;

  // staging mapping: thread -> channel pair (c0,c0+1), t-quarter th (16 t)
  const int c0 = (tid & 127) * 2;
  const int th = tid >> 7;  // 0..3
  const int cw = tid & 127;
  unsigned int* l32 = (unsigned int*)lds;

  // prologue: stage sub 0 into xs
  {
    const float* xpA = xb + (size_t)c0 * TT + t0 + th * 16;
    const float* xpB = xpA + TT;
#pragma unroll
    for (int k = 0; k < 4; ++k) {
      const float4 va = reinterpret_cast<const float4*>(xpA)[k];
      const float4 vb4 = reinterpret_cast<const float4*>(xpB)[k];
      const int tb = th * 16 + k * 4;
      l32[(tb + 0) * 132 + cw] = pack2(va.x, vb4.x);
      l32[(tb + 1) * 132 + cw] = pack2(va.y, vb4.y);
      l32[(tb + 2) * 132 + cw] = pack2(va.z, vb4.z);
      l32[(tb + 3) * 132 + cw] = pack2(va.w, vb4.w);
    }
  }

  for (int sub = 0; sub < 2; ++sub) {
    __syncthreads();  // barrier A: xs ready

    v4f acc[4][2];

    // ---- k-pass ----
#pragma unroll
    for (int i = 0; i < 4; ++i)
#pragma unroll
      for (int j = 0; j < 2; ++j) acc[i][j] = (v4f){0.f, 0.f, 0.f, 0.f};
#pragma unroll
    for (int ks = 0; ks < 8; ++ks) {
      v8s af[4], bfu[2];
#pragma unroll
      for (int rt = 0; rt < 4; ++rt)
        af[rt] = *(const v8s*)(wk + (size_t)(rt * 16 + cl) * 256 + ks * 32 + q * 8);
#pragma unroll
      for (int ct = 0; ct < 2; ++ct)
        bfu[ct] = *(const v8s*)&lds[(tw0 + ct * 16 + cl) * 264 + ks * 32 + q * 8];
#pragma unroll
      for (int rt = 0; rt < 4; ++rt)
#pragma unroll
        for (int ct = 0; ct < 2; ++ct)
          acc[rt][ct] = MFMA(af[rt], bfu[ct], acc[rt][ct]);
    }
    // exp + e -> R2 (swizzled), z accumulate
#pragma unroll
    for (int rt = 0; rt < 4; ++rt)
#pragma unroll
      for (int ct = 0; ct < 2; ++ct)
#pragma unroll
        for (int reg = 0; reg < 4; ++reg) {
          const int row = rt * 16 + q * 4 + reg;
          const float e = __expf(acc[rt][ct][reg]);
          zacc[rt][reg] += e;
          ekw[swz_w(row, ct * 16 + cl)] = f2bf(e);
        }

    // ---- v-pass (reuses acc registers) ----
#pragma unroll
    for (int i = 0; i < 4; ++i)
#pragma unroll
      for (int j = 0; j < 2; ++j) acc[i][j] = (v4f){0.f, 0.f, 0.f, 0.f};
#pragma unroll
    for (int ks = 0; ks < 8; ++ks) {
      v8s af[4], bfu[2];
#pragma unroll
      for (int rt = 0; rt < 4; ++rt)
        af[rt] = *(const v8s*)(wv + (size_t)(rt * 16 + cl) * 256 + ks * 32 + q * 8);
#pragma unroll
      for (int ct = 0; ct < 2; ++ct)
        bfu[ct] = *(const v8s*)&lds[(tw0 + ct * 16 + cl) * 264 + ks * 32 + q * 8];
#pragma unroll
      for (int rt = 0; rt < 4; ++rt)
#pragma unroll
        for (int ct = 0; ct < 2; ++ct)
          acc[rt][ct] = MFMA(af[rt], bfu[ct], acc[rt][ct]);
    }
    __syncthreads();  // barrier B: all waves done reading xs

    // ---- v -> R1 overlay (swizzled) ----
#pragma unroll
    for (int rt = 0; rt < 4; ++rt)
#pragma unroll
      for (int ct = 0; ct < 2; ++ct)
#pragma unroll
        for (int reg = 0; reg < 4; ++reg) {
          const int row = rt * 16 + q * 4 + reg;
          vbw_[swz_w(row, ct * 16 + cl)] = f2bf(acc[rt][ct][reg]);
        }

    // ---- prefetch next sub's x (issued after acc is dead; lands during U) ----
    float4 nxA[4], nxB[4];
    if (sub == 0) {
      const float* xpA = xb + (size_t)c0 * TT + (t0 + 64) + th * 16;
      const float* xpB = xpA + TT;
#pragma unroll
      for (int k = 0; k < 4; ++k) {
        nxA[k] = reinterpret_cast<const float4*>(xpA)[k];
        nxB[k] = reinterpret_cast<const float4*>(xpB)[k];
      }
    }
    __syncthreads();  // barrier C: e and v of both slices visible

    // ---- U rows [tw0, tw0+32) += e @ v^T over both slices ----
#pragma unroll
    for (int s = 0; s < 2; ++s) {
      const unsigned short* eks = &lds[16896 + h * 4096 + s * 2048];
      const unsigned short* vbs = &lds[h * 4096 + s * 2048];
      v8s afu[2], bfv[4];
#pragma unroll
      for (int ur = 0; ur < 2; ++ur)
        afu[ur] = *(const v8s*)&eks[swz_r(tw0 + ur * 16 + cl, q)];
#pragma unroll
      for (int uc = 0; uc < 4; ++uc)
        bfv[uc] = *(const v8s*)&vbs[swz_r(uc * 16 + cl, q)];
#pragma unroll
      for (int ur = 0; ur < 2; ++ur)
#pragma unroll
        for (int uc = 0; uc < 4; ++uc)
          Uacc[ur][uc] = MFMA(afu[ur], bfv[uc], Uacc[ur][uc]);
    }

    // ---- stage prefetched x into R1 (overwrites v buffers) ----
    if (sub == 0) {
      __syncthreads();  // barrier D: all waves done reading v
#pragma unroll
      for (int k = 0; k < 4; ++k) {
        const int tb = th * 16 + k * 4;
        l32[(tb + 0) * 132 + cw] = pack2(nxA[k].x, nxB[k].x);
        l32[(tb + 1) * 132 + cw] = pack2(nxA[k].y, nxB[k].y);
        l32[(tb + 2) * 132 + cw] = pack2(nxA[k].z, nxB[k].z);
        l32[(tb + 3) * 132 + cw] = pack2(nxA[k].w, nxB[k].w);
      }
    }
  }

  // ---- Z: butterfly over the 16 col-lanes, store per wave ----
#pragma unroll
  for (int m = 1; m < 16; m <<= 1)
#pragma unroll
    for (int rt = 0; rt < 4; ++rt)
#pragma unroll
      for (int reg = 0; reg < 4; ++reg)
        zacc[rt][reg] += __shfl_xor(zacc[rt][reg], m, 64);
  if (cl == 0) {
    for (int rt = 0; rt < 4; ++rt)
      for (int reg = 0; reg < 4; ++reg)
        ws[OFF_ZPART + (size_t)bi * 512 + w * 64 + rt * 16 + q * 4 + reg] =
            zacc[rt][reg];
  }
  // ---- U partial store (wave pair covers rows; no duplication) ----
  float* Up = ws + OFF_UPART + (size_t)bi * 16384 + h * 4096;
#pragma unroll
  for (int ur = 0; ur < 2; ++ur)
#pragma unroll
    for (int uc = 0; uc < 4; ++uc)
#pragma unroll
      for (int reg = 0; reg < 4; ++reg)
        Up[(tw0 + ur * 16 + q * 4 + reg) * 64 + uc * 16 + cl] =
            Uacc[ur][uc][reg];
}

// ---------------------------------------------------------------------------
// k2: reduce 64 partial blocks per batch (U) / 128 wave-partials (Z);
// kv = U / Z[d].
// ---------------------------------------------------------------------------
__global__ void k2_reduce_kv(float* __restrict__ ws) {
  const int bi = blockIdx.x;  // 0..511
  const int bh = bi >> 4, j = bi & 15;
  const int b = bh >> 2, h = bh & 3;
  const int tid = threadIdx.x;

  __shared__ float zinv[64];
  if (tid < 64) {
    float z = 0.f;
#pragma unroll 4
    for (int cb = 0; cb < 64; ++cb) {
      const size_t base = OFF_ZPART + (size_t)(b * 64 + cb) * 512;
      z += ws[base + (h * 2 + 0) * 64 + tid] + ws[base + (h * 2 + 1) * 64 + tid];
    }
    zinv[tid] = 1.0f / z;
  }
  __syncthreads();

  const int idx = j * 256 + tid;  // 0..4095 in (b,h)
  const int d = idx >> 6;
  float s = 0.f;
#pragma unroll 4
  for (int cb = 0; cb < 64; ++cb)
    s += ws[OFF_UPART + (size_t)(b * 64 + cb) * 16384 + h * 4096 + idx];
  ws[OFF_KV + (size_t)(b * 4 + h) * 4096 + idx] = s * zinv[d];
}

// ---------------------------------------------------------------------------
// k3a: P^T[b][c][h*64+e] = sum_d kv[b,h,d,e] * Wq[h*192+d][c]  (bf16, transposed
// so k3b's B-frags are contiguous along c2)
// ---------------------------------------------------------------------------
__global__ void k3a_P(const float* __restrict__ Wpre, float* __restrict__ ws) {
  const int bi = blockIdx.x;  // b*256 + he
  const int b = bi >> 8, he = bi & 255;
  const int h = he >> 6, e = he & 63;
  const int c = threadIdx.x;
  const float* kvp = ws + OFF_KV + (size_t)(b * 4 + h) * 4096;
  float acc = 0.f;
#pragma unroll 8
  for (int d = 0; d < 64; ++d)
    acc += kvp[d * 64 + e] * Wpre[(size_t)(h * 192 + d) * 256 + c];
  ((unsigned short*)(ws + OFF_PT))[(size_t)b * 65536 + (size_t)c * 256 + he] =
      f2bf(acc);
}

// ---------------------------------------------------------------------------
// k3b: M[b][o][c] = scale * (Wproj @ P)  via MFMA; grid = 8b x 4 cg x 4 rg.
// ---------------------------------------------------------------------------
__global__ __launch_bounds__(256, 2) void k3b_M(const float* __restrict__ scale,
                                                float* __restrict__ ws) {
  const int bi = blockIdx.x;
  const int b = bi >> 4, cg = (bi >> 2) & 3, rg = bi & 3;
  const int tid = threadIdx.x, w = tid >> 6, lane = tid & 63, q = lane >> 4,
            cl = lane & 15;
  const unsigned short* wpj = (const unsigned short*)(ws + OFF_WPJ);
  const unsigned short* pt =
      (const unsigned short*)(ws + OFF_PT) + (size_t)b * 65536;
  v4f acc[4];
#pragma unroll
  for (int j = 0; j < 4; ++j) acc[j] = (v4f){0.f, 0.f, 0.f, 0.f};
#pragma unroll
  for (int ks = 0; ks < 8; ++ks) {
    const v8s af = *(const v8s*)(wpj + (size_t)(rg * 64 + w * 16 + cl) * 256 +
                                 ks * 32 + q * 8);
    v8s bfu[4];
#pragma unroll
    for (int ct = 0; ct < 4; ++ct)
      bfu[ct] = *(const v8s*)(pt + (size_t)(cg * 64 + ct * 16 + cl) * 256 +
                              ks * 32 + q * 8);
#pragma unroll
    for (int ct = 0; ct < 4; ++ct) acc[ct] = MFMA(af, bfu[ct], acc[ct]);
  }
  const float s = scale[0];
  unsigned short* mbf = (unsigned short*)(ws + OFF_MBF);
#pragma unroll
  for (int ct = 0; ct < 4; ++ct)
#pragma unroll
    for (int reg = 0; reg < 4; ++reg) {
      const int o = rg * 64 + w * 16 + q * 4 + reg;
      const int c = cg * 64 + ct * 16 + cl;
      mbf[((size_t)b * 256 + o) * 256 + c] = f2bf(s * acc[ct][reg]);
    }
}

// ---------------------------------------------------------------------------
// k4: out = LN_C( M@x + scale*b_proj + x ) * gamma + beta, MFMA + fused LN.
// Grid: 8b x 256 chunks of 32 t; 4 waves, wave w = rows w*64..w*64+63.
// ---------------------------------------------------------------------------
__global__ __launch_bounds__(256, 2) void k4_proj_ln(
    const float* __restrict__ x, const float* __restrict__ bproj,
    const float* __restrict__ scale, const float* __restrict__ gamma,
    const float* __restrict__ beta, const float* __restrict__ ws,
    float* __restrict__ out) {
  __shared__ unsigned short xs[32 * 264];
  __shared__ float red1[128], red2[128], muA[32], rsA[32];
  const int bi = blockIdx.x, b = bi >> 8, tc = bi & 255;
  const int tg0 = tc * 32;
  const int tid = threadIdx.x, w = tid >> 6, lane = tid & 63, q = lane >> 4,
            cl = lane & 15;
  const float* xb = x + (size_t)b * (CC * TT);

  // stage x[c][tg0..+32) -> xs[t][c] bf16, packed u32 channel-pair writes
  {
    const int c0 = (tid & 127) * 2;
    const int th = tid >> 7;  // 0..1
    const float* xpA = xb + (size_t)c0 * TT + tg0 + th * 16;
    const float* xpB = xpA + TT;
    unsigned int* x32 = (unsigned int*)xs;
    const int cw = c0 >> 1;
#pragma unroll
    for (int k = 0; k < 4; ++k) {
      const float4 va = reinterpret_cast<const float4*>(xpA)[k];
      const float4 vb = reinterpret_cast<const float4*>(xpB)[k];
      const int tb = th * 16 + k * 4;
      x32[(tb + 0) * 132 + cw] = pack2(va.x, vb.x);
      x32[(tb + 1) * 132 + cw] = pack2(va.y, vb.y);
      x32[(tb + 2) * 132 + cw] = pack2(va.z, vb.z);
      x32[(tb + 3) * 132 + cw] = pack2(va.w, vb.w);
    }
  }
  __syncthreads();

  const unsigned short* mbf =
      (const unsigned short*)(ws + OFF_MBF) + (size_t)b * 65536;
  v4f acc[4][2];
#pragma unroll
  for (int i = 0; i < 4; ++i)
#pragma unroll
    for (int j = 0; j < 2; ++j) acc[i][j] = (v4f){0.f, 0.f, 0.f, 0.f};
#pragma unroll
  for (int ks = 0; ks < 8; ++ks) {
    v8s af[4], bfu[2];
#pragma unroll
    for (int rt = 0; rt < 4; ++rt)
      af[rt] = *(const v8s*)(mbf + (size_t)(w * 64 + rt * 16 + cl) * 256 +
                             ks * 32 + q * 8);
#pragma unroll
    for (int ct = 0; ct < 2; ++ct)
      bfu[ct] = *(const v8s*)&xs[(ct * 16 + cl) * 264 + ks * 32 + q * 8];
#pragma unroll
    for (int rt = 0; rt < 4; ++rt)
#pragma unroll
      for (int ct = 0; ct < 2; ++ct)
        acc[rt][ct] = MFMA(af[rt], bfu[ct], acc[rt][ct]);
  }

  // y = ctx_proj + scale*b_proj + residual (residual from bf16 xs)
  const float s = scale[0];
#pragma unroll
  for (int rt = 0; rt < 4; ++rt)
#pragma unroll
    for (int reg = 0; reg < 4; ++reg) {
      const int o = w * 64 + rt * 16 + q * 4 + reg;
      const float sb = s * bproj[o];
#pragma unroll
      for (int ct = 0; ct < 2; ++ct) {
        const int tl = ct * 16 + cl;
        acc[rt][ct][reg] += sb + bf2f(xs[tl * 264 + o]);
      }
    }

  // LN sums over C: per-lane 16 rows -> butterfly over q -> cross-wave LDS
#pragma unroll
  for (int ct = 0; ct < 2; ++ct) {
    float s1 = 0.f, s2 = 0.f;
#pragma unroll
    for (int rt = 0; rt < 4; ++rt)
#pragma unroll
      for (int reg = 0; reg < 4; ++reg) {
        const float v = acc[rt][ct][reg];
        s1 += v;
        s2 += v * v;
      }
    s1 += __shfl_xor(s1, 16, 64);
    s1 += __shfl_xor(s1, 32, 64);
    s2 += __shfl_xor(s2, 16, 64);
    s2 += __shfl_xor(s2, 32, 64);
    if (q == 0) {
      red1[w * 32 + ct * 16 + cl] = s1;
      red2[w * 32 + ct * 16 + cl] = s2;
    }
  }
  __syncthreads();
  if (tid < 32) {
    const float s1 = red1[tid] + red1[32 + tid] + red1[64 + tid] + red1[96 + tid];
    const float s2 = red2[tid] + red2[32 + tid] + red2[64 + tid] + red2[96 + tid];
    const float mu = s1 * (1.f / 256.f);
    const float var = s2 * (1.f / 256.f) - mu * mu;
    muA[tid] = mu;
    rsA[tid] = rsqrtf(var + EPSF);
  }
  __syncthreads();

  float* ob = out + (size_t)b * (CC * TT) + tg0;
#pragma unroll
  for (int rt = 0; rt < 4; ++rt)
#pragma unroll
    for (int reg = 0; reg < 4; ++reg) {
      const int o = w * 64 + rt * 16 + q * 4 + reg;
      const float g = gamma[o], bt = beta[o];
#pragma unroll
      for (int ct = 0; ct < 2; ++ct) {
        const int tl = ct * 16 + cl;
        ob[(size_t)o * TT + tl] = (acc[rt][ct][reg] - muA[tl]) * rsA[tl] * g + bt;
      }
    }
}

// ---------------------------------------------------------------------------
extern "C" void kernel_launch(void* const* d_in, const int* in_sizes, int n_in,
                              void* d_out, int out_size, void* d_ws,
                              size_t ws_size, hipStream_t stream) {
  (void)in_sizes; (void)n_in; (void)out_size; (void)ws_size;
  const float* x = (const float*)d_in[0];
  const float* Wpre = (const float*)d_in[1];
  const float* Wproj = (const float*)d_in[2];
  const float* bproj = (const float*)d_in[3];
  const float* scale = (const float*)d_in[4];
  const float* gamma = (const float*)d_in[5];
  const float* beta = (const float*)d_in[6];
  float* out = (float*)d_out;
  float* ws = (float*)d_ws;

  hipLaunchKernelGGL(k0_pack, dim3(768), dim3(256), 0, stream, Wpre, Wproj, ws);
  hipLaunchKernelGGL(k1_kv, dim3(512), dim3(512), 0, stream, x, ws);
  hipLaunchKernelGGL(k2_reduce_kv, dim3(512), dim3(256), 0, stream, ws);
  hipLaunchKernelGGL(k3a_P, dim3(BB * 256), dim3(256), 0, stream, Wpre, ws);
  hipLaunchKernelGGL(k3b_M, dim3(128), dim3(256), 0, stream, scale, ws);
  hipLaunchKernelGGL(k4_proj_ln, dim3(BB * 128 * 2), dim3(256), 0, stream, x,
                     bproj, scale, gamma, beta, ws, out);
}

// Round 9
// 237.219 us; speedup vs baseline: 1.2195x; 1.2195x over previous
//
#include <hip/hip_runtime.h>
#include <hip/hip_bf16.h>
#include <math.h>

// Problem constants
#define BB 8
#define CC 256
#define TT 8192
#define EPSF 1e-5f

typedef short v8s __attribute__((ext_vector_type(8)));
typedef float v4f __attribute__((ext_vector_type(4)));

#define MFMA(a, b, c) __builtin_amdgcn_mfma_f32_16x16x32_bf16((a), (b), (c), 0, 0, 0)

// MFMA 16x16x32 bf16 fragment conventions (m89/m91 verified):
//   A[m][k]: m = lane&15, k = (lane>>4)*8 + j   (8 contiguous k per lane)
//   B[k][n]: n = lane&15, k = (lane>>4)*8 + j
//   C/D:     col = lane&15, row = (lane>>4)*4 + reg
//
// REGISTER MODEL (r1-r8): 512-thread blocks are pinned at <=128 arch VGPRs;
// demand above spills ~150MB/pass (r1/r3/r4/r8). Occupancy = 512-unified /
// (VGPR+AGPR): fat waves (~176+) -> 2 waves/SIMD regardless of LDS (r8
// proved halving LDS alone does nothing). v7: QUARTER the per-wave tile
// (16 d-rows/wave, acc[1][4]+Uacc[1][4], ~90 regs) -> 4+ waves/SIMD,
// 2 blocks/CU. x staged once per head-PAIR block (2x reads, L3-resident).

// Workspace layout (float offsets); ~20.3 MB (same as round-0 anchor)
#define OFF_WKV 0               // Wkv bf16 [h][type][64][256]  -> 131072 ushort
#define OFF_WPJ 65536           // Wproj bf16 [256][256]        -> 65536 ushort
#define OFF_UPART 98304         // fp32 [512 blk][2 lh][64][64] -> 4194304 floats
#define OFF_ZPART 4292608       // fp32 [512 blk][2 lh][64]     -> 65536 floats
#define OFF_KV 4358144          // fp32 [b][h][64 d][64 e]
#define OFF_PT 4489216          // Pt bf16 [b][c][256 c2]       -> 524288 ushort
#define OFF_MBF 4751360         // M bf16 [b][o][c]             -> 524288 ushort

__device__ __forceinline__ unsigned short f2bf(float f) {
  __hip_bfloat16 h = __float2bfloat16(f);
  return __builtin_bit_cast(unsigned short, h);
}
__device__ __forceinline__ float bf2f(unsigned short u) {
  return __bfloat162float(__builtin_bit_cast(__hip_bfloat16, u));
}
__device__ __forceinline__ unsigned int pack2(float lo, float hi) {
  return (unsigned int)f2bf(lo) | ((unsigned int)f2bf(hi) << 16);
}

// ---------------------------------------------------------------------------
// k0: pack weights to bf16. rows 0..511: Wkv[h][type][d][c]; rows 512..767: Wproj.
// ---------------------------------------------------------------------------
__global__ void k0_pack(const float* __restrict__ Wpre,
                        const float* __restrict__ Wproj,
                        float* __restrict__ ws) {
  const int r = blockIdx.x;
  const int c = threadIdx.x;
  if (r < 512) {
    const int h = r >> 7, type = (r >> 6) & 1, d = r & 63;
    const int src = h * 192 + 64 + type * 64 + d;
    ((unsigned short*)(ws + OFF_WKV))[r * 256 + c] = f2bf(Wpre[(size_t)src * 256 + c]);
  } else {
    const int rr = r - 512;
    ((unsigned short*)(ws + OFF_WPJ))[rr * 256 + c] = f2bf(Wproj[(size_t)rr * 256 + c]);
  }
}

// ---------------------------------------------------------------------------
// k1 (v7, slim waves): grid 512 = 8b x 32 chunks(256t) x 2 head-pairs;
// 8 waves = 2 local heads x 4 d-quarters. Wave (lh, dq) per 64-t sub:
//   [A] xs ready
//   k-pass:  acc[1][4] = W_k rows [dq*16,+16) x 64t   (32 MFMA)
//            exp -> zacc[4], e -> e-buf rows [dq*16,+16)
//   v-pass:  acc reused = W_v rows x 64t              (32 MFMA) -> v-buf
//   [B] e/v of the head complete; xs fully consumed
//   issue next-sub global loads (land under U)
//   U rows [dq*16,+16) x 64e += e @ v^T over 64t      (8 MFMA, ks=2)
//   pack+write staged x -> xs
// LDS: xs[64][264] (33792 B) + 2 heads x (e[64][72] + v[64][72]) (36864 B)
//    = 70656 B -> 2 blocks/CU. Regs ~90 -> 4+ waves/SIMD. 2 barriers/sub.
// Hazards: xs reads end before B; staging writes after B; new-xs readers
// wait at next A. e/v written (A..B), read (B..A'); next write after A'. OK.
// ---------------------------------------------------------------------------
__global__ __launch_bounds__(512) void k1_kv(const float* __restrict__ x,
                                             float* __restrict__ ws) {
  __shared__ unsigned short lds[35328];  // 70656 B

  const int tid = threadIdx.x;
  const int w = tid >> 6, lane = tid & 63, q = lane >> 4, cl = lane & 15;
  const int lh = w >> 2, dq = w & 3;
  const int bi = blockIdx.x;  // 0..511
  const int b = bi >> 6, rem = bi & 63, chunk = rem >> 1, hp = rem & 1;
  const int h = hp * 2 + lh;
  const int t0 = chunk * 256;
  const float* xb = x + (size_t)b * (CC * TT);
  const unsigned short* wk =
      (const unsigned short*)(ws + OFF_WKV) + (size_t)((h * 2 + 0) * 64) * 256;
  const unsigned short* wv =
      (const unsigned short*)(ws + OFF_WKV) + (size_t)((h * 2 + 1) * 64) * 256;
  unsigned short* eb = &lds[16896 + lh * 9216];         // e [64][72]
  unsigned short* vb = &lds[16896 + lh * 9216 + 4608];  // v [64][72]

  v4f Uacc[4];
#pragma unroll
  for (int j = 0; j < 4; ++j) Uacc[j] = (v4f){0.f, 0.f, 0.f, 0.f};
  float zacc[4] = {0.f, 0.f, 0.f, 0.f};

  // staging mapping: thread -> channel pair (c0,c0+1), t-quarter th (16 t)
  const int c0 = (tid & 127) * 2;
  const int th = tid >> 7;  // 0..3
  const int cw = tid & 127;
  unsigned int* l32 = (unsigned int*)lds;

  // prologue: stage sub 0 into xs
  {
    const float* xpA = xb + (size_t)c0 * TT + t0 + th * 16;
    const float* xpB = xpA + TT;
#pragma unroll
    for (int k = 0; k < 4; ++k) {
      const float4 va = reinterpret_cast<const float4*>(xpA)[k];
      const float4 vb4 = reinterpret_cast<const float4*>(xpB)[k];
      const int tb = th * 16 + k * 4;
      l32[(tb + 0) * 132 + cw] = pack2(va.x, vb4.x);
      l32[(tb + 1) * 132 + cw] = pack2(va.y, vb4.y);
      l32[(tb + 2) * 132 + cw] = pack2(va.z, vb4.z);
      l32[(tb + 3) * 132 + cw] = pack2(va.w, vb4.w);
    }
  }

  for (int sub = 0; sub < 4; ++sub) {
    __syncthreads();  // barrier A: xs ready

    v4f acc[4];

    // ---- k-pass: rows [dq*16,+16) x 64 t ----
#pragma unroll
    for (int j = 0; j < 4; ++j) acc[j] = (v4f){0.f, 0.f, 0.f, 0.f};
#pragma unroll
    for (int ks = 0; ks < 8; ++ks) {
      const v8s af =
          *(const v8s*)(wk + (size_t)(dq * 16 + cl) * 256 + ks * 32 + q * 8);
      v8s bfu[4];
#pragma unroll
      for (int ct = 0; ct < 4; ++ct)
        bfu[ct] = *(const v8s*)&lds[(ct * 16 + cl) * 264 + ks * 32 + q * 8];
#pragma unroll
      for (int ct = 0; ct < 4; ++ct) acc[ct] = MFMA(af, bfu[ct], acc[ct]);
    }
    // exp + e -> e-buf, z accumulate (rows dq*16 + q*4 + reg)
#pragma unroll
    for (int ct = 0; ct < 4; ++ct)
#pragma unroll
      for (int reg = 0; reg < 4; ++reg) {
        const float e = __expf(acc[ct][reg]);
        zacc[reg] += e;
        eb[(dq * 16 + q * 4 + reg) * 72 + ct * 16 + cl] = f2bf(e);
      }

    // ---- v-pass (reuses acc) ----
#pragma unroll
    for (int j = 0; j < 4; ++j) acc[j] = (v4f){0.f, 0.f, 0.f, 0.f};
#pragma unroll
    for (int ks = 0; ks < 8; ++ks) {
      const v8s af =
          *(const v8s*)(wv + (size_t)(dq * 16 + cl) * 256 + ks * 32 + q * 8);
      v8s bfu[4];
#pragma unroll
      for (int ct = 0; ct < 4; ++ct)
        bfu[ct] = *(const v8s*)&lds[(ct * 16 + cl) * 264 + ks * 32 + q * 8];
#pragma unroll
      for (int ct = 0; ct < 4; ++ct) acc[ct] = MFMA(af, bfu[ct], acc[ct]);
    }
#pragma unroll
    for (int ct = 0; ct < 4; ++ct)
#pragma unroll
      for (int reg = 0; reg < 4; ++reg)
        vb[(dq * 16 + q * 4 + reg) * 72 + ct * 16 + cl] = f2bf(acc[ct][reg]);

    __syncthreads();  // barrier B: e/v complete, xs consumed

    // ---- issue next sub's loads (land under the U MFMAs) ----
    float4 nxA[4], nxB[4];
    if (sub < 3) {
      const float* xpA = xb + (size_t)c0 * TT + (t0 + (sub + 1) * 64) + th * 16;
      const float* xpB = xpA + TT;
#pragma unroll
      for (int k = 0; k < 4; ++k) {
        nxA[k] = reinterpret_cast<const float4*>(xpA)[k];
        nxB[k] = reinterpret_cast<const float4*>(xpB)[k];
      }
    }

    // ---- U rows [dq*16,+16) x 64 e over 64 t ----
#pragma unroll
    for (int ks = 0; ks < 2; ++ks) {
      const v8s afu =
          *(const v8s*)&eb[(dq * 16 + cl) * 72 + ks * 32 + q * 8];
      v8s bfv[4];
#pragma unroll
      for (int uc = 0; uc < 4; ++uc)
        bfv[uc] = *(const v8s*)&vb[(uc * 16 + cl) * 72 + ks * 32 + q * 8];
#pragma unroll
      for (int uc = 0; uc < 4; ++uc)
        Uacc[uc] = MFMA(afu, bfv[uc], Uacc[uc]);
    }

    // ---- write staged x into xs (readers wait at next barrier A) ----
    if (sub < 3) {
#pragma unroll
      for (int k = 0; k < 4; ++k) {
        const int tb = th * 16 + k * 4;
        l32[(tb + 0) * 132 + cw] = pack2(nxA[k].x, nxB[k].x);
        l32[(tb + 1) * 132 + cw] = pack2(nxA[k].y, nxB[k].y);
        l32[(tb + 2) * 132 + cw] = pack2(nxA[k].z, nxB[k].z);
        l32[(tb + 3) * 132 + cw] = pack2(nxA[k].w, nxB[k].w);
      }
    }
  }

  // ---- Z: butterfly over the 16 col-lanes, store from cl==0 ----
#pragma unroll
  for (int m = 1; m < 16; m <<= 1)
#pragma unroll
    for (int reg = 0; reg < 4; ++reg)
      zacc[reg] += __shfl_xor(zacc[reg], m, 64);
  if (cl == 0) {
#pragma unroll
    for (int reg = 0; reg < 4; ++reg)
      ws[OFF_ZPART + (size_t)bi * 128 + lh * 64 + dq * 16 + q * 4 + reg] =
          zacc[reg];
  }
  // ---- U partial store ----
  float* Up = ws + OFF_UPART + (size_t)bi * 8192 + lh * 4096;
#pragma unroll
  for (int uc = 0; uc < 4; ++uc)
#pragma unroll
    for (int reg = 0; reg < 4; ++reg)
      Up[(dq * 16 + q * 4 + reg) * 64 + uc * 16 + cl] = Uacc[uc][reg];
}

// ---------------------------------------------------------------------------
// k2: reduce 32 partial blocks per (b,h); kv = U / Z[d].
// Partials live at bi = b*64 + chunk*2 + (h>>1), slot lh = h&1.
// ---------------------------------------------------------------------------
__global__ void k2_reduce_kv(float* __restrict__ ws) {
  const int bi = blockIdx.x;  // 0..511
  const int bh = bi >> 4, j = bi & 15;
  const int b = bh >> 2, h = bh & 3;
  const int hp = h >> 1, lh = h & 1;
  const int tid = threadIdx.x;

  __shared__ float zinv[64];
  if (tid < 64) {
    float z = 0.f;
#pragma unroll 4
    for (int cb = 0; cb < 32; ++cb)
      z += ws[OFF_ZPART + (size_t)(b * 64 + cb * 2 + hp) * 128 + lh * 64 + tid];
    zinv[tid] = 1.0f / z;
  }
  __syncthreads();

  const int idx = j * 256 + tid;  // 0..4095 in (b,h)
  const int d = idx >> 6;
  float s = 0.f;
#pragma unroll 4
  for (int cb = 0; cb < 32; ++cb)
    s += ws[OFF_UPART + (size_t)(b * 64 + cb * 2 + hp) * 8192 + lh * 4096 + idx];
  ws[OFF_KV + (size_t)(b * 4 + h) * 4096 + idx] = s * zinv[d];
}

// ---------------------------------------------------------------------------
// k3a: P^T[b][c][h*64+e] = sum_d kv[b,h,d,e] * Wq[h*192+d][c]  (bf16, transposed
// so k3b's B-frags are contiguous along c2)
// ---------------------------------------------------------------------------
__global__ void k3a_P(const float* __restrict__ Wpre, float* __restrict__ ws) {
  const int bi = blockIdx.x;  // b*256 + he
  const int b = bi >> 8, he = bi & 255;
  const int h = he >> 6, e = he & 63;
  const int c = threadIdx.x;
  const float* kvp = ws + OFF_KV + (size_t)(b * 4 + h) * 4096;
  float acc = 0.f;
#pragma unroll 8
  for (int d = 0; d < 64; ++d)
    acc += kvp[d * 64 + e] * Wpre[(size_t)(h * 192 + d) * 256 + c];
  ((unsigned short*)(ws + OFF_PT))[(size_t)b * 65536 + (size_t)c * 256 + he] =
      f2bf(acc);
}

// ---------------------------------------------------------------------------
// k3b: M[b][o][c] = scale * (Wproj @ P)  via MFMA; grid = 8b x 4 c-groups.
// (round-0 proven version)
// ---------------------------------------------------------------------------
__global__ __launch_bounds__(256, 2) void k3b_M(const float* __restrict__ scale,
                                                float* __restrict__ ws) {
  const int bi = blockIdx.x, b = bi >> 2, cg = bi & 3;
  const int tid = threadIdx.x, w = tid >> 6, lane = tid & 63, q = lane >> 4,
            cl = lane & 15;
  const unsigned short* wpj = (const unsigned short*)(ws + OFF_WPJ);
  const unsigned short* pt =
      (const unsigned short*)(ws + OFF_PT) + (size_t)b * 65536;
  v4f acc[4][4];
#pragma unroll
  for (int i = 0; i < 4; ++i)
#pragma unroll
    for (int j = 0; j < 4; ++j) acc[i][j] = (v4f){0.f, 0.f, 0.f, 0.f};
#pragma unroll
  for (int ks = 0; ks < 8; ++ks) {
    v8s af[4], bfu[4];
#pragma unroll
    for (int rt = 0; rt < 4; ++rt)
      af[rt] = *(const v8s*)(wpj + (size_t)(w * 64 + rt * 16 + cl) * 256 +
                             ks * 32 + q * 8);
#pragma unroll
    for (int ct = 0; ct < 4; ++ct)
      bfu[ct] = *(const v8s*)(pt + (size_t)(cg * 64 + ct * 16 + cl) * 256 +
                              ks * 32 + q * 8);
#pragma unroll
    for (int rt = 0; rt < 4; ++rt)
#pragma unroll
      for (int ct = 0; ct < 4; ++ct)
        acc[rt][ct] = MFMA(af[rt], bfu[ct], acc[rt][ct]);
  }
  const float s = scale[0];
  unsigned short* mbf = (unsigned short*)(ws + OFF_MBF);
#pragma unroll
  for (int rt = 0; rt < 4; ++rt)
#pragma unroll
    for (int ct = 0; ct < 4; ++ct)
#pragma unroll
      for (int reg = 0; reg < 4; ++reg) {
        const int o = w * 64 + rt * 16 + q * 4 + reg;
        const int c = cg * 64 + ct * 16 + cl;
        mbf[((size_t)b * 256 + o) * 256 + c] = f2bf(s * acc[rt][ct][reg]);
      }
}

// ---------------------------------------------------------------------------
// k4: out = LN_C( M@x + scale*b_proj + x ) * gamma + beta, MFMA + fused LN.
// Grid: 8b x 128 chunks of 64 t; 4 waves. (round-0 proven version)
// ---------------------------------------------------------------------------
__global__ __launch_bounds__(256, 2) void k4_proj_ln(
    const float* __restrict__ x, const float* __restrict__ bproj,
    const float* __restrict__ scale, const float* __restrict__ gamma,
    const float* __restrict__ beta, const float* __restrict__ ws,
    float* __restrict__ out) {
  __shared__ unsigned short xs[64 * 264];
  __shared__ float red1[256], red2[256], muA[64], rsA[64];
  const int bi = blockIdx.x, b = bi >> 7, tc = bi & 127;
  const int tg0 = tc * 64;
  const int tid = threadIdx.x, w = tid >> 6, lane = tid & 63, q = lane >> 4,
            cl = lane & 15;
  const float* xb = x + (size_t)b * (CC * TT);

  // stage x[c][tg0..+64) -> xs[t][c] bf16
  {
    const int c = tid;
    const float* xp = xb + (size_t)c * TT + tg0;
#pragma unroll
    for (int j = 0; j < 16; ++j) {
      const float4 v4 = reinterpret_cast<const float4*>(xp)[j];
      const int tb = j * 4;
      xs[(tb + 0) * 264 + c] = f2bf(v4.x);
      xs[(tb + 1) * 264 + c] = f2bf(v4.y);
      xs[(tb + 2) * 264 + c] = f2bf(v4.z);
      xs[(tb + 3) * 264 + c] = f2bf(v4.w);
    }
  }
  __syncthreads();

  const unsigned short* mbf =
      (const unsigned short*)(ws + OFF_MBF) + (size_t)b * 65536;
  v4f acc[4][4];
#pragma unroll
  for (int i = 0; i < 4; ++i)
#pragma unroll
    for (int j = 0; j < 4; ++j) acc[i][j] = (v4f){0.f, 0.f, 0.f, 0.f};
#pragma unroll
  for (int ks = 0; ks < 8; ++ks) {
    v8s af[4], bfu[4];
#pragma unroll
    for (int rt = 0; rt < 4; ++rt)
      af[rt] = *(const v8s*)(mbf + (size_t)(w * 64 + rt * 16 + cl) * 256 +
                             ks * 32 + q * 8);
#pragma unroll
    for (int ct = 0; ct < 4; ++ct)
      bfu[ct] = *(const v8s*)&xs[(ct * 16 + cl) * 264 + ks * 32 + q * 8];
#pragma unroll
    for (int rt = 0; rt < 4; ++rt)
#pragma unroll
      for (int ct = 0; ct < 4; ++ct)
        acc[rt][ct] = MFMA(af[rt], bfu[ct], acc[rt][ct]);
  }

  // y = ctx_proj + scale*b_proj + residual (residual from bf16 xs)
  const float s = scale[0];
#pragma unroll
  for (int rt = 0; rt < 4; ++rt)
#pragma unroll
    for (int reg = 0; reg < 4; ++reg) {
      const int o = w * 64 + rt * 16 + q * 4 + reg;
      const float sb = s * bproj[o];
#pragma unroll
      for (int ct = 0; ct < 4; ++ct) {
        const int tl = ct * 16 + cl;
        acc[rt][ct][reg] += sb + bf2f(xs[tl * 264 + o]);
      }
    }

  // LN sums over C: per-lane 16 rows -> butterfly over q -> cross-wave LDS
#pragma unroll
  for (int ct = 0; ct < 4; ++ct) {
    float s1 = 0.f, s2 = 0.f;
#pragma unroll
    for (int rt = 0; rt < 4; ++rt)
#pragma unroll
      for (int reg = 0; reg < 4; ++reg) {
        const float v = acc[rt][ct][reg];
        s1 += v;
        s2 += v * v;
      }
    s1 += __shfl_xor(s1, 16, 64);
    s1 += __shfl_xor(s1, 32, 64);
    s2 += __shfl_xor(s2, 16, 64);
    s2 += __shfl_xor(s2, 32, 64);
    if (q == 0) {
      red1[w * 64 + ct * 16 + cl] = s1;
      red2[w * 64 + ct * 16 + cl] = s2;
    }
  }
  __syncthreads();
  if (tid < 64) {
    const float s1 = red1[tid] + red1[64 + tid] + red1[128 + tid] + red1[192 + tid];
    const float s2 = red2[tid] + red2[64 + tid] + red2[128 + tid] + red2[192 + tid];
    const float mu = s1 * (1.f / 256.f);
    const float var = s2 * (1.f / 256.f) - mu * mu;
    muA[tid] = mu;
    rsA[tid] = rsqrtf(var + EPSF);
  }
  __syncthreads();

  float* ob = out + (size_t)b * (CC * TT) + tg0;
#pragma unroll
  for (int rt = 0; rt < 4; ++rt)
#pragma unroll
    for (int reg = 0; reg < 4; ++reg) {
      const int o = w * 64 + rt * 16 + q * 4 + reg;
      const float g = gamma[o], bt = beta[o];
#pragma unroll
      for (int ct = 0; ct < 4; ++ct) {
        const int tl = ct * 16 + cl;
        ob[(size_t)o * TT + tl] = (acc[rt][ct][reg] - muA[tl]) * rsA[tl] * g + bt;
      }
    }
}

// ---------------------------------------------------------------------------
extern "C" void kernel_launch(void* const* d_in, const int* in_sizes, int n_in,
                              void* d_out, int out_size, void* d_ws,
                              size_t ws_size, hipStream_t stream) {
  (void)in_sizes; (void)n_in; (void)out_size; (void)ws_size;
  const float* x = (const float*)d_in[0];
  const float* Wpre = (const float*)d_in[1];
  const float* Wproj = (const float*)d_in[2];
  const float* bproj = (const float*)d_in[3];
  const float* scale = (const float*)d_in[4];
  const float* gamma = (const float*)d_in[5];
  const float* beta = (const float*)d_in[6];
  float* out = (float*)d_out;
  float* ws = (float*)d_ws;

  hipLaunchKernelGGL(k0_pack, dim3(768), dim3(256), 0, stream, Wpre, Wproj, ws);
  hipLaunchKernelGGL(k1_kv, dim3(512), dim3(512), 0, stream, x, ws);
  hipLaunchKernelGGL(k2_reduce_kv, dim3(512), dim3(256), 0, stream, ws);
  hipLaunchKernelGGL(k3a_P, dim3(BB * 256), dim3(256), 0, stream, Wpre, ws);
  hipLaunchKernelGGL(k3b_M, dim3(32), dim3(256), 0, stream, scale, ws);
  hipLaunchKernelGGL(k4_proj_ln, dim3(BB * 128), dim3(256), 0, stream, x, bproj,
                     scale, gamma, beta, ws, out);
}